// Round 5
// baseline (6112.071 us; speedup 1.0000x reference)
//
#include <hip/hip_runtime.h>
#include <stdint.h>

// CharRNN MI355X — 1-wave blocks, register-resident W_hh, chunk-pipelined
// exchange (no LDS in the main loop, no restage, no rendezvous).
//   K1 k_prep : proj[v][h] = embedding[v,:] @ W_ih + b_h  (VOCAB=64 table)
//   K1b k_prep2: W_ho -> bf16 MFMA-fragment table (wof) in ws
//   K2 k_rnn  : persistent 256 blocks x 64 threads (1 wave, 1/CU).
//     Block (gi,gj): batch rows gi*32..+32, hidden cols gj*32..+32.
//     - W_hh slice (1024x32) lives in 256 VGPRs as 64 B-fragments (2 nt x
//       32 chunks), loaded once via an LDS-staged reorder at startup.
//     - Recurrence MFMA chain (32 chunks of K=32, 4 mfma each) consumes
//       producer p's ring data AT chain position p: A-frags (16B/lane) are
//       agent-loaded straight from the ring, prefetched 4 chunks ahead.
//       Chain starts at producer gj+1 (staggered across blocks; own chunk
//       last -> trivially ready).
//     - Per-step flag cost: one 32-lane flag gather (1 RTT) + ballot ->
//       ready mask; targeted wait_flag only for stragglers.
//     - Producer release: 8 packed dword stores -> s_waitcnt vmcnt(0) ->
//       per-producer flag (own 128B line). All data/flag ops use the
//       round-0-proven agent-scope relaxed atomics.
//     - Logits every 16 steps: proven 16-rows x 1-t x 64-voc mapping,
//       4 voc-tiles chained per kb; W_ho frags re-read from wof (L1/L2
//       cacheable, read-only).
// d_ws: proj f32 @0 (256KB) | flags @262144 (32KB) | wof @524288 (128KB)
//       | ring bf16 @1MB (16MB)

#define BATCH 256
#define SEQ   512
#define HID   1024
#define VOC   64
#define EMB   256
#define FINAL_OFF (BATCH * SEQ * VOC)   // 8388608
#define RING_SLOTS 32
#define BH (BATCH * HID)

typedef __attribute__((ext_vector_type(8))) short short8;
typedef __attribute__((ext_vector_type(4))) float f32x4;
typedef unsigned long long u64;

__device__ inline unsigned short f2bf(float f) {
  union { float f; unsigned u; } v; v.f = f;
  unsigned u = v.u;
  return (unsigned short)((u + 0x7FFFu + ((u >> 16) & 1u)) >> 16);  // RNE
}

// ---- agent-scope (MALL-point) ops — the PROVEN coherence class -------------
__device__ inline u64 cload64(const unsigned short* p) {
  return __hip_atomic_load((const u64*)p, __ATOMIC_RELAXED,
                           __HIP_MEMORY_SCOPE_AGENT);
}
__device__ inline void cstore32(unsigned short* p, unsigned v) {
  __hip_atomic_store((unsigned*)p, v, __ATOMIC_RELAXED,
                     __HIP_MEMORY_SCOPE_AGENT);
}
__device__ inline unsigned fload(const unsigned* p) {
  return __hip_atomic_load(p, __ATOMIC_RELAXED, __HIP_MEMORY_SCOPE_AGENT);
}
__device__ inline void fstore(unsigned* p, unsigned v) {
  __hip_atomic_store(p, v, __ATOMIC_RELAXED, __HIP_MEMORY_SCOPE_AGENT);
}
__device__ __forceinline__ void wait_flag(const unsigned* __restrict__ f,
                                          unsigned target) {
  int g = 0;
  while (fload(f) < target) {
    __builtin_amdgcn_s_sleep(1);
    if (++g > (1 << 16)) break;          // bailout: wrong answer beats a hang
  }
}

// ---------------- K1: projection table -------------------------------------
__global__ __launch_bounds__(256) void k_prep(const float* __restrict__ emb,
                                              const float* __restrict__ Wih,
                                              const float* __restrict__ bh,
                                              float* __restrict__ proj) {
  __shared__ float es[EMB];
  const int v = blockIdx.x >> 2;        // 0..63
  const int p = blockIdx.x & 3;         // h-quarter
  const int tid = threadIdx.x;
  es[tid] = emb[v * EMB + tid];
  __syncthreads();
  const int h = p * 256 + tid;
  float acc = bh[h];
  for (int e = 0; e < EMB; ++e) acc += es[e] * Wih[e * HID + h];
  proj[v * HID + h] = acc;
}

// ---------------- K1b: W_ho bf16 fragment table ----------------------------
// entry e = ((kb*4+q)*4+vt)*16 + l15 ; elems j: Who[(kb*32+q*8+j)*VOC+vt*16+l15]
__global__ __launch_bounds__(256) void k_prep2(const float* __restrict__ Who,
                                               unsigned short* __restrict__ wof) {
  const int e = blockIdx.x * 256 + threadIdx.x;   // 0..8191
  const int l15 = e & 15, vt = (e >> 4) & 3, qq = (e >> 6) & 3, kb = e >> 8;
  #pragma unroll
  for (int j = 0; j < 8; ++j)
    wof[e * 8 + j] = f2bf(Who[(kb * 32 + qq * 8 + j) * VOC + vt * 16 + l15]);
}

// ---------------- K2: persistent recurrence + inline logits ----------------
// LDS (startup only): w_stage 65536 | p_lds 8192
__global__ __launch_bounds__(64, 1) void k_rnn(
    const int* __restrict__ x, const float* __restrict__ Whh,
    const float* __restrict__ proj, const unsigned short* __restrict__ wof,
    const float* __restrict__ bo, unsigned short* __restrict__ ring,
    float* __restrict__ out, float* __restrict__ final_out,
    unsigned int* __restrict__ flags) {
  extern __shared__ char smem[];
  unsigned short* w_stage = (unsigned short*)smem;          // 65536
  float*          p_lds   = (float*)(smem + 65536);         // 8192

  const int tid = threadIdx.x, bid = blockIdx.x;
  const int gi = bid & 7, gj = bid >> 3;                    // group / col-slice
  const int row0 = gi * 32;
  const int l15 = tid & 15, q = tid >> 4;                   // q in 0..3

  // ---- startup: stage W_hh slice -> LDS in B-fragment order ----
  for (int u = tid; u < 32768; u += 64) {
    int k = u >> 5, n = u & 31;
    int c = k >> 5, qq = (k >> 3) & 3, j = k & 7;
    int nt = n >> 4, p15 = n & 15;
    w_stage[(((c * 2 + nt) * 4 + qq) * 16 + p15) * 8 + j] =
        f2bf(Whh[k * HID + gj * 32 + n]);
  }
  for (int u = tid; u < 2048; u += 64)
    p_lds[u] = proj[(u >> 5) * HID + gj * 32 + (u & 31)];
  __syncthreads();

  // ---- B-fragments -> registers, in rotated chain order ----
  const int s = (gj + 1) & 31;                  // chain starts at producer gj+1
  short8 bf0[32], bf1[32];
  const char* wsb = (const char*)w_stage;
  #pragma unroll
  for (int i = 0; i < 32; ++i) {
    int c = (s + i) & 31;
    bf0[i] = *(const short8*)(wsb + c * 2048 +        q * 256 + l15 * 16);
    bf1[i] = *(const short8*)(wsb + c * 2048 + 1024 + q * 256 + l15 * 16);
  }

  float bias[4];
  #pragma unroll
  for (int vt = 0; vt < 4; ++vt) bias[vt] = bo[vt * 16 + l15];

  unsigned* flags_g = flags + gi * 32 * 32;     // 32 producers x 128B lines
  unsigned* myflag  = flags_g + gj * 32;

  unsigned ready = 0;
  for (int t = 0; t < SEQ; ++t) {
    int xv = (tid < 32) ? x[(row0 + tid) * SEQ + t] : 0;
    f32x4 a00 = {0.f, 0.f, 0.f, 0.f}, a01 = {0.f, 0.f, 0.f, 0.f};
    f32x4 a10 = {0.f, 0.f, 0.f, 0.f}, a11 = {0.f, 0.f, 0.f, 0.f};

    // ---- recurrence: chunk-pipelined MFMA over K, straight from ring ----
    if (t > 0) {
      const unsigned short* slotR = ring + (size_t)((t - 1) & 31) * BH;
      const unsigned short* b0 = slotR + (size_t)(row0 + l15) * HID + q * 8;
      const unsigned short* b1 = b0 + 16 * HID;              // mt=1 rows
      u64 p0a[4], p0b[4], p1a[4], p1b[4];
      #pragma unroll
      for (int i = 0; i < 4; ++i) {                          // prologue: 4 deep
        int pp = (s + i) & 31;
        if (!((ready >> pp) & 1)) { wait_flag(flags_g + pp * 32, (unsigned)t);
                                    ready |= 1u << pp; }
        p0a[i] = cload64(b0 + pp * 32); p0b[i] = cload64(b0 + pp * 32 + 4);
        p1a[i] = cload64(b1 + pp * 32); p1b[i] = cload64(b1 + pp * 32 + 4);
      }
      #pragma unroll
      for (int i = 0; i < 32; ++i) {
        const int sl = i & 3;
        u64 c0a = p0a[sl], c0b = p0b[sl], c1a = p1a[sl], c1b = p1b[sl];
        if (i < 28) {                                        // prefetch i+4
          int pp = (s + i + 4) & 31;
          if (!((ready >> pp) & 1)) { wait_flag(flags_g + pp * 32, (unsigned)t);
                                      ready |= 1u << pp; }
          p0a[sl] = cload64(b0 + pp * 32); p0b[sl] = cload64(b0 + pp * 32 + 4);
          p1a[sl] = cload64(b1 + pp * 32); p1b[sl] = cload64(b1 + pp * 32 + 4);
        }
        union { u64 d[2]; short8 s8; } ca, cb;
        ca.d[0] = c0a; ca.d[1] = c0b;
        cb.d[0] = c1a; cb.d[1] = c1b;
        a00 = __builtin_amdgcn_mfma_f32_16x16x32_bf16(ca.s8, bf0[i], a00, 0, 0, 0);
        a01 = __builtin_amdgcn_mfma_f32_16x16x32_bf16(ca.s8, bf1[i], a01, 0, 0, 0);
        a10 = __builtin_amdgcn_mfma_f32_16x16x32_bf16(cb.s8, bf0[i], a10, 0, 0, 0);
        a11 = __builtin_amdgcn_mfma_f32_16x16x32_bf16(cb.s8, bf1[i], a11, 0, 0, 0);
      }
    }

    // ---- epilogue: h_t = tanh(proj[x_t] + acc) ----
    unsigned short* slotW = ring + (size_t)(t & 31) * BH;
    float hv[2][2][4];
    #pragma unroll
    for (int mt = 0; mt < 2; ++mt)
      #pragma unroll
      for (int rr = 0; rr < 4; ++rr) {
        int row = mt * 16 + q * 4 + rr;
        int xi = __shfl(xv, row);
        #pragma unroll
        for (int nt = 0; nt < 2; ++nt) {
          float av = mt == 0 ? (nt == 0 ? a00[rr] : a01[rr])
                             : (nt == 0 ? a10[rr] : a11[rr]);
          float v = tanhf(p_lds[xi * 32 + nt * 16 + l15] + av);
          hv[mt][nt][rr] = v;
          if (t == SEQ - 1)
            final_out[(size_t)(row0 + row) * HID + gj * 32 + nt * 16 + l15] = v;
        }
      }
    // publish: packed col-pairs; even l15 lanes store mt=0, odd store mt=1
    #pragma unroll
    for (int mt = 0; mt < 2; ++mt)
      #pragma unroll
      for (int nt = 0; nt < 2; ++nt)
        #pragma unroll
        for (int rr = 0; rr < 4; ++rr) {
          unsigned myb = f2bf(hv[mt][nt][rr]);
          unsigned oth = (unsigned)__shfl_xor((int)myb, 1);
          unsigned pk = (l15 & 1) ? (oth | (myb << 16)) : (myb | (oth << 16));
          if ((l15 & 1) == mt)
            cstore32(slotW + (size_t)(row0 + mt * 16 + q * 4 + rr) * HID +
                         gj * 32 + nt * 16 + (l15 & ~1), pk);
        }
    asm volatile("s_waitcnt vmcnt(0)" ::: "memory");   // release: data at MALL
    if (tid == 0) fstore(myflag, (unsigned)(t + 1));

    // ---- chunked logits every 16 steps: 16 rows x 1 t x 64 voc ----
    if ((t & 15) == 15) {
      int tsel  = (t - 15) + (gj >> 1);
      int rbase = row0 + (gj & 1) * 16;
      {
        int g2 = 0;
        for (;;) {                                     // all flags >= tsel+1
          unsigned fl = fload(flags_g + (tid & 31) * 32);
          if (__all(fl >= (unsigned)(tsel + 1))) break;
          __builtin_amdgcn_s_sleep(1);
          if (++g2 > (1 << 16)) break;
        }
      }
      const unsigned short* hs = ring + (size_t)(tsel & 31) * BH +
                                 (size_t)(rbase + l15) * HID + q * 8;
      f32x4 lc0 = {0.f, 0.f, 0.f, 0.f}, lc1 = {0.f, 0.f, 0.f, 0.f};
      f32x4 lc2 = {0.f, 0.f, 0.f, 0.f}, lc3 = {0.f, 0.f, 0.f, 0.f};
      #pragma unroll
      for (int kb = 0; kb < 32; ++kb) {
        union { u64 d[2]; short8 s8; } c;
        c.d[0] = cload64(hs + kb * 32);
        c.d[1] = cload64(hs + kb * 32 + 4);
        const char* wb = (const char*)wof + (size_t)((kb * 4 + q) * 4) * 256 +
                         l15 * 16;
        lc0 = __builtin_amdgcn_mfma_f32_16x16x32_bf16(c.s8, *(const short8*)(wb), lc0, 0, 0, 0);
        lc1 = __builtin_amdgcn_mfma_f32_16x16x32_bf16(c.s8, *(const short8*)(wb + 256), lc1, 0, 0, 0);
        lc2 = __builtin_amdgcn_mfma_f32_16x16x32_bf16(c.s8, *(const short8*)(wb + 512), lc2, 0, 0, 0);
        lc3 = __builtin_amdgcn_mfma_f32_16x16x32_bf16(c.s8, *(const short8*)(wb + 768), lc3, 0, 0, 0);
      }
      #pragma unroll
      for (int rr = 0; rr < 4; ++rr) {
        size_t ob = ((size_t)(rbase + q * 4 + rr) * SEQ + tsel) * VOC + l15;
        out[ob     ] = lc0[rr] + bias[0];
        out[ob + 16] = lc1[rr] + bias[1];
        out[ob + 32] = lc2[rr] + bias[2];
        out[ob + 48] = lc3[rr] + bias[3];
      }
      // no reuse hazard: 32-slot ring, logits lag <= 15 steps
    }

    // ---- flag gather for next step (one RTT, ballot -> ready mask) ----
    if (t < SEQ - 1) {
      unsigned fv = fload(flags_g + (tid & 31) * 32);
      u64 bl = __ballot(fv >= (unsigned)(t + 1));
      ready = (unsigned)bl & (unsigned)(bl >> 32);
    }
  }
}

// ---------------- launch ----------------------------------------------------
extern "C" void kernel_launch(void* const* d_in, const int* in_sizes, int n_in,
                              void* d_out, int out_size, void* d_ws, size_t ws_size,
                              hipStream_t stream) {
  const int*   x   = (const int*)d_in[0];
  const float* emb = (const float*)d_in[1];
  const float* Wih = (const float*)d_in[2];
  const float* Whh = (const float*)d_in[3];
  const float* bh  = (const float*)d_in[4];
  const float* Who = (const float*)d_in[5];
  const float* bo  = (const float*)d_in[6];
  float* out = (float*)d_out;

  char* ws = (char*)d_ws;
  float*          proj  = (float*)ws;                        // 262144 B
  unsigned int*   flags = (unsigned int*)(ws + 262144);      // 32768 B
  unsigned short* wof   = (unsigned short*)(ws + 524288);    // 131072 B
  unsigned short* ring  = (unsigned short*)(ws + (1 << 20)); // 16 MiB

  size_t need = (size_t)(1 << 20) + (size_t)RING_SLOTS * BATCH * HID * 2;
  if (ws_size < need) return;  // diagnostic fail (absmax) instead of a fault

  (void)hipFuncSetAttribute(reinterpret_cast<const void*>(k_rnn),
                            hipFuncAttributeMaxDynamicSharedMemorySize, 98304);

  k_prep<<<256, 256, 0, stream>>>(emb, Wih, bh, proj);
  k_prep2<<<32, 256, 0, stream>>>(Who, wof);
  hipMemsetAsync(flags, 0, 32768, stream);
  k_rnn<<<256, 64, 98304, stream>>>(x, Whh, proj, wof, bo, ring,
                                    out, out + FINAL_OFF, flags);
}

// Round 6
// 4679.134 us; speedup vs baseline: 1.3062x; 1.3062x over previous
//
#include <hip/hip_runtime.h>
#include <stdint.h>

// CharRNN MI355X — 4-wave blocks, LDS W_hh, chunk-pipelined ring exchange.
//   K1 k_prep  : proj[v][h] = embedding[v,:] @ W_ih + b_h  (VOCAB=64 table)
//   K1b k_prep2: W_ho -> bf16 MFMA-fragment table (wof)
//   K2 k_rnn   : persistent 256 blocks x 256 threads (4 waves, 1/CU).
//     Block (gi,gj): batch rows gi*32..+32, hidden cols gj*32..+32.
//     Wave decomposition: (mt = row-half) x (kh = K-half):
//       wave (mt,kh) computes rows mt*16..+16 x all 32 cols, K = kh*512..+512
//       (16 chunks of K=32, = 16 producers), 2 MFMAs/chunk (nt=0,1).
//     - W_hh slice in LDS (round-0 verified B-fragment layout, 64KB).
//     - A-frags agent-loaded STRAIGHT from ring (no restage, no h_lds):
//       all 16 chunks' loads issued up-front (32 outstanding) so the ~900cy
//       MALL latency hides under the MFMA chain. Rotation (gj&15)+1 puts
//       own-block chunk last.
//     - Flags are PER PRODUCER WAVE (gj,mt): 64 flags/group, own 128B lines.
//       Publish: wave's 8 packed stores -> s_waitcnt vmcnt(0) -> flag store
//       (no intra-block rendezvous on the publish path). Consumer: one
//       64-lane ballot gather + targeted straggler waits.
//     - K-halves combined via small SoA conflict-free LDS reduce (double-
//       buffered by t&1); one __syncthreads per step.
//     - Logits every 16 steps: round-0's proven 16-rows x 1-t x 64-voc
//       mapping, A from ring, B from wof table (round-5-proven layout).
//   All cross-block data/flag ops: round-0-proven agent-scope relaxed atomics.
// d_ws: proj @0 (256KB) | flags @262144 (64KB) | wof @524288 (128KB)
//       | ring bf16 @1MB (16MB)

#define BATCH 256
#define SEQ   512
#define HID   1024
#define VOC   64
#define EMB   256
#define FINAL_OFF (BATCH * SEQ * VOC)   // 8388608
#define RING_SLOTS 32
#define BH (BATCH * HID)

typedef __attribute__((ext_vector_type(8))) short short8;
typedef __attribute__((ext_vector_type(4))) float f32x4;
typedef unsigned long long u64;

__device__ inline unsigned short f2bf(float f) {
  union { float f; unsigned u; } v; v.f = f;
  unsigned u = v.u;
  return (unsigned short)((u + 0x7FFFu + ((u >> 16) & 1u)) >> 16);  // RNE
}

// ---- agent-scope (MALL-point) ops — the PROVEN coherence class -------------
__device__ inline u64 cload64(const unsigned short* p) {
  return __hip_atomic_load((const u64*)p, __ATOMIC_RELAXED,
                           __HIP_MEMORY_SCOPE_AGENT);
}
__device__ inline void cstore32(unsigned short* p, unsigned v) {
  __hip_atomic_store((unsigned*)p, v, __ATOMIC_RELAXED,
                     __HIP_MEMORY_SCOPE_AGENT);
}
__device__ inline unsigned fload(const unsigned* p) {
  return __hip_atomic_load(p, __ATOMIC_RELAXED, __HIP_MEMORY_SCOPE_AGENT);
}
__device__ inline void fstore(unsigned* p, unsigned v) {
  __hip_atomic_store(p, v, __ATOMIC_RELAXED, __HIP_MEMORY_SCOPE_AGENT);
}
__device__ __forceinline__ void wait_flag(const unsigned* __restrict__ f,
                                          unsigned target) {
  int g = 0;
  while (fload(f) < target) {
    __builtin_amdgcn_s_sleep(1);
    if (++g > (1 << 16)) break;          // bailout: wrong answer beats a hang
  }
}

// ---------------- K1: projection table -------------------------------------
__global__ __launch_bounds__(256) void k_prep(const float* __restrict__ emb,
                                              const float* __restrict__ Wih,
                                              const float* __restrict__ bh,
                                              float* __restrict__ proj) {
  __shared__ float es[EMB];
  const int v = blockIdx.x >> 2;        // 0..63
  const int p = blockIdx.x & 3;         // h-quarter
  const int tid = threadIdx.x;
  es[tid] = emb[v * EMB + tid];
  __syncthreads();
  const int h = p * 256 + tid;
  float acc = bh[h];
  for (int e = 0; e < EMB; ++e) acc += es[e] * Wih[e * HID + h];
  proj[v * HID + h] = acc;
}

// ---------------- K1b: W_ho bf16 fragment table (round-5-proven) -----------
// entry e = ((kb*4+q)*4+vt)*16 + l15 ; elems j: Who[(kb*32+q*8+j)*VOC+vt*16+l15]
__global__ __launch_bounds__(256) void k_prep2(const float* __restrict__ Who,
                                               unsigned short* __restrict__ wof) {
  const int e = blockIdx.x * 256 + threadIdx.x;   // 0..8191
  const int l15 = e & 15, vt = (e >> 4) & 3, qq = (e >> 6) & 3, kb = e >> 8;
  #pragma unroll
  for (int j = 0; j < 8; ++j)
    wof[e * 8 + j] = f2bf(Who[(kb * 32 + qq * 8 + j) * VOC + vt * 16 + l15]);
}

// ---------------- K2: persistent recurrence + inline logits ----------------
// LDS: w_lds 65536 | p_lds 8192 | red 8192  (total 81920)
__global__ __launch_bounds__(256, 1) void k_rnn(
    const int* __restrict__ x, const float* __restrict__ Whh,
    const float* __restrict__ proj, const unsigned short* __restrict__ wof,
    const float* __restrict__ bo, unsigned short* __restrict__ ring,
    float* __restrict__ out, float* __restrict__ final_out,
    unsigned int* __restrict__ flags) {
  extern __shared__ char smem[];
  unsigned short* w_lds = (unsigned short*)smem;            // 65536
  float*          p_lds = (float*)(smem + 65536);           // 8192
  float*          red   = (float*)(smem + 73728);           // 8192

  const int tid = threadIdx.x, bid = blockIdx.x;
  const int gi = bid & 7, gj = bid >> 3;                    // group / col-slice
  const int row0 = gi * 32;
  const int lane = tid & 63, wv = tid >> 6;
  const int mt = wv & 1, kh = wv >> 1;                      // row-half / K-half
  const int l15 = lane & 15, q = lane >> 4;
  const int g16 = gj & 15;

  // W_hh column slice -> LDS bf16 B-fragment order (round-0 verified).
  for (int it = 0; it < 128; ++it) {
    int u = it * 256 + tid;
    int n = u & 31, j8 = (u >> 5) & 7, qq = (u >> 8) & 3, kb = u >> 10;
    w_lds[((kb * 4 + qq) * 32 + n) * 8 + j8] =
        f2bf(Whh[(kb * 32 + qq * 8 + j8) * HID + gj * 32 + n]);
  }
  // proj slice [64 vocab][32 cols] -> LDS f32 (once).
  for (int it = 0; it < 8; ++it) {
    int u = it * 256 + tid;
    p_lds[u] = proj[(u >> 5) * HID + gj * 32 + (u & 31)];
  }
  __syncthreads();

  // 64 flags per group (one per producer-wave (gj',mt')), 128B lines.
  unsigned* flags_g = flags + gi * 64 * 32;
  const char* bb = (const char*)w_lds + (q * 32 + l15) * 16;  // nt=0 base
  const float bias = bo[wv * 16 + l15];

  for (int t = 0; t < SEQ; ++t) {
    int xv = (kh == 0 && lane < 32) ? x[(row0 + lane) * SEQ + t] : 0;
    f32x4 acc0 = {0.f, 0.f, 0.f, 0.f}, acc1 = {0.f, 0.f, 0.f, 0.f};

    // ---- K-loop: 16 chunks, A straight from ring, loads fully up-front ----
    if (t > 0) {
      const unsigned short* slotR = ring + (size_t)((t - 1) & 31) * BH;
      const unsigned short* ab =
          slotR + (size_t)(row0 + mt * 16 + l15) * HID + q * 8;
      unsigned fv = fload(flags_g + lane * 32);
      u64 ready = __ballot(fv >= (unsigned)t);      // bit lane == flag lane
      u64 pa[16], pb[16];
      #pragma unroll
      for (int i = 0; i < 16; ++i) {
        int pp = kh * 16 + ((g16 + 1 + i) & 15);
        int bit = pp * 2 + mt;
        if (!((ready >> bit) & 1)) {
          wait_flag(flags_g + bit * 32, (unsigned)t);
          ready |= 1ull << bit;
        }
        pa[i] = cload64(ab + pp * 32);
        pb[i] = cload64(ab + pp * 32 + 4);
      }
      #pragma unroll
      for (int i = 0; i < 16; ++i) {
        int pp = kh * 16 + ((g16 + 1 + i) & 15);
        short8 b0 = *(const short8*)(bb + pp * 2048);
        short8 b1 = *(const short8*)(bb + pp * 2048 + 256);
        union { u64 d[2]; short8 s8; } c;
        c.d[0] = pa[i]; c.d[1] = pb[i];
        acc0 = __builtin_amdgcn_mfma_f32_16x16x32_bf16(c.s8, b0, acc0, 0, 0, 0);
        acc1 = __builtin_amdgcn_mfma_f32_16x16x32_bf16(c.s8, b1, acc1, 0, 0, 0);
      }
    }

    // ---- combine K-halves: kh1 -> LDS (SoA, conflict-free, dbuf) ----------
    float* redb = red + ((t & 1) * 2 + mt) * 512;   // [8 j][64 lane] f32
    if (kh == 1) {
      #pragma unroll
      for (int j = 0; j < 4; ++j) {
        redb[j * 64 + lane]       = acc0[j];
        redb[(j + 4) * 64 + lane] = acc1[j];
      }
    }
    __syncthreads();

    // ---- epilogue (kh0 waves): h = tanh(proj + acc), publish + flag -------
    if (kh == 0) {
      #pragma unroll
      for (int j = 0; j < 4; ++j) {
        acc0[j] += redb[j * 64 + lane];
        acc1[j] += redb[(j + 4) * 64 + lane];
      }
      unsigned short* slotW = ring + (size_t)(t & 31) * BH;
      float hv[2][4];
      #pragma unroll
      for (int ntl = 0; ntl < 2; ++ntl)
        #pragma unroll
        for (int r = 0; r < 4; ++r) {
          int row = mt * 16 + q * 4 + r;
          int xi = __shfl(xv, row);
          float av = ntl ? acc1[r] : acc0[r];
          float v = tanhf(p_lds[xi * 32 + ntl * 16 + l15] + av);
          hv[ntl][r] = v;
          if (t == SEQ - 1)
            final_out[(size_t)(row0 + row) * HID + gj * 32 + ntl * 16 + l15] = v;
        }
      #pragma unroll
      for (int ntl = 0; ntl < 2; ++ntl)
        #pragma unroll
        for (int r = 0; r < 4; ++r) {
          unsigned myb = f2bf(hv[ntl][r]);
          unsigned oth = (unsigned)__shfl_xor((int)myb, 1);
          if ((l15 & 1) == 0)
            cstore32(slotW + (size_t)(row0 + mt * 16 + q * 4 + r) * HID +
                         gj * 32 + ntl * 16 + l15,
                     myb | (oth << 16));
        }
      asm volatile("s_waitcnt vmcnt(0)" ::: "memory");  // release to MALL
      if (lane == 0)
        fstore(flags_g + (gj * 2 + mt) * 32, (unsigned)(t + 1));
    }

    // ---- chunked logits every 16 steps: 16 rows x 1 t x 64 voc ------------
    if ((t & 15) == 15) {
      int tsel  = (t - 15) + (gj >> 1);
      int rbase = row0 + (gj & 1) * 16;
      int g2 = 0;
      while (!__all(fload(flags_g + lane * 32) >= (unsigned)(tsel + 1))) {
        __builtin_amdgcn_s_sleep(1);
        if (++g2 > (1 << 16)) break;
      }
      const unsigned short* hs = ring + (size_t)(tsel & 31) * BH +
                                 (size_t)(rbase + l15) * HID + q * 8;
      const char* wofb =
          (const char*)wof + (size_t)(((q * 4 + wv) * 16) + l15) * 16;
      f32x4 lcE = {0.f, 0.f, 0.f, 0.f}, lcO = {0.f, 0.f, 0.f, 0.f};
      #pragma unroll
      for (int kb = 0; kb < 32; ++kb) {
        union { u64 d[2]; short8 s8; } c;
        c.d[0] = cload64(hs + kb * 32);
        c.d[1] = cload64(hs + kb * 32 + 4);
        short8 wf8 = *(const short8*)(wofb + (size_t)kb * 4096);
        if (kb & 1)
          lcO = __builtin_amdgcn_mfma_f32_16x16x32_bf16(c.s8, wf8, lcO, 0, 0, 0);
        else
          lcE = __builtin_amdgcn_mfma_f32_16x16x32_bf16(c.s8, wf8, lcE, 0, 0, 0);
      }
      #pragma unroll
      for (int rr = 0; rr < 4; ++rr) {
        size_t ob = ((size_t)(rbase + q * 4 + rr) * SEQ + tsel) * VOC +
                    wv * 16 + l15;
        out[ob] = lcE[rr] + lcO[rr] + bias;
      }
      // no reuse hazard: skew <= 1 step, logits lag <= 15, ring depth 32
    }
  }
}

// ---------------- launch ----------------------------------------------------
extern "C" void kernel_launch(void* const* d_in, const int* in_sizes, int n_in,
                              void* d_out, int out_size, void* d_ws, size_t ws_size,
                              hipStream_t stream) {
  const int*   x   = (const int*)d_in[0];
  const float* emb = (const float*)d_in[1];
  const float* Wih = (const float*)d_in[2];
  const float* Whh = (const float*)d_in[3];
  const float* bh  = (const float*)d_in[4];
  const float* Who = (const float*)d_in[5];
  const float* bo  = (const float*)d_in[6];
  float* out = (float*)d_out;

  char* ws = (char*)d_ws;
  float*          proj  = (float*)ws;                        // 262144 B
  unsigned int*   flags = (unsigned int*)(ws + 262144);      // 65536 B
  unsigned short* wof   = (unsigned short*)(ws + 524288);    // 131072 B
  unsigned short* ring  = (unsigned short*)(ws + (1 << 20)); // 16 MiB

  size_t need = (size_t)(1 << 20) + (size_t)RING_SLOTS * BATCH * HID * 2;
  if (ws_size < need) return;  // diagnostic fail (absmax) instead of a fault

  (void)hipFuncSetAttribute(reinterpret_cast<const void*>(k_rnn),
                            hipFuncAttributeMaxDynamicSharedMemorySize, 81920);

  k_prep<<<256, 256, 0, stream>>>(emb, Wih, bh, proj);
  k_prep2<<<32, 256, 0, stream>>>(Who, wof);
  hipMemsetAsync(flags, 0, 65536, stream);
  k_rnn<<<256, 256, 81920, stream>>>(x, Whh, proj, wof, bo, ring,
                                     out, out + FINAL_OFF, flags);
}

// Round 7
// 2937.697 us; speedup vs baseline: 2.0806x; 1.5928x over previous
//
#include <hip/hip_runtime.h>
#include <stdint.h>

// CharRNN MI355X — round-0 skeleton + on-chain cost removal.
//   K1 k_prep  : proj[v][h] = embedding[v,:] @ W_ih + b_h  (VOCAB=64 table)
//   K1b k_prep2: W_ho -> bf16 MFMA-fragment table (wof)  [r6-proven layout]
//   K2 k_rnn   : persistent 256 blocks (1/CU). Block (gi,gj): batch rows
//               gi*32..+32, hidden cols gj*32..+32. W_hh slice bf16 in LDS.
//               Exchange: agent-scope ring + atomicAdd barrier (r0-proven).
//   Changes vs r0 (each on the serial per-step chain):
//     1. tanhf -> branch-free exp identity (v_exp_f32 + rcp).
//     2. logits de-lumped: 2 kb-chunks/step, PRE-barrier (fills barrier
//        wait), A prefetched 1 step ahead (latency absorbed by barrier's
//        vmcnt(0) drain). Pacing starts at t=tsel+1 so required flags are
//        already confirmed by the previous barrier -> no rendezvous, no
//        wait-all. Reads end at tsel+17 < overwrite at tsel+32 (safe).
//        Post-loop drain finishes the last window.
//     3. recurrence accumulators 2 -> 4 chains (dep depth 16 -> 8 MFMA);
//        W_ho B-frags from wof table (kills wf[32] remat pressure).
// d_ws: proj f32 @0 (256KB) | cnt @262144 (1KB) | wof @524288 (128KB)
//       | ring bf16 @1MB (16MB)

#define BATCH 256
#define SEQ   512
#define HID   1024
#define VOC   64
#define EMB   256
#define FINAL_OFF (BATCH * SEQ * VOC)   // 8388608
#define RING_SLOTS 32
#define BH (BATCH * HID)

typedef __attribute__((ext_vector_type(8))) short short8;
typedef __attribute__((ext_vector_type(4))) float f32x4;
typedef unsigned long long u64;

__device__ inline unsigned short f2bf(float f) {
  union { float f; unsigned u; } v; v.f = f;
  unsigned u = v.u;
  return (unsigned short)((u + 0x7FFFu + ((u >> 16) & 1u)) >> 16);  // RNE
}

// branch-free tanh: 1 - 2/(e^{2x}+1). Saturates correctly at +/-inf.
__device__ __forceinline__ float ftanh(float v) {
  float e = __expf(2.0f * v);
  return fmaf(-2.0f, __builtin_amdgcn_rcpf(e + 1.0f), 1.0f);
}

// ---- agent-scope (MALL-point) ops — the PROVEN coherence class -------------
__device__ inline u64 cload64(const unsigned short* p) {
  return __hip_atomic_load((const u64*)p, __ATOMIC_RELAXED,
                           __HIP_MEMORY_SCOPE_AGENT);
}
__device__ inline void cstore32(unsigned short* p, unsigned v) {
  __hip_atomic_store((unsigned*)p, v, __ATOMIC_RELAXED,
                     __HIP_MEMORY_SCOPE_AGENT);
}

// ---------------- K1: projection table -------------------------------------
__global__ __launch_bounds__(256) void k_prep(const float* __restrict__ emb,
                                              const float* __restrict__ Wih,
                                              const float* __restrict__ bh,
                                              float* __restrict__ proj) {
  __shared__ float es[EMB];
  const int v = blockIdx.x >> 2;        // 0..63
  const int p = blockIdx.x & 3;         // h-quarter
  const int tid = threadIdx.x;
  es[tid] = emb[v * EMB + tid];
  __syncthreads();
  const int h = p * 256 + tid;
  float acc = bh[h];
  for (int e = 0; e < EMB; ++e) acc += es[e] * Wih[e * HID + h];
  proj[v * HID + h] = acc;
}

// ---------------- K1b: W_ho bf16 fragment table (r6-proven) ----------------
// entry e = ((kb*4+q)*4+vt)*16 + l15 ; elems j: Who[(kb*32+q*8+j)*VOC+vt*16+l15]
__global__ __launch_bounds__(256) void k_prep2(const float* __restrict__ Who,
                                               unsigned short* __restrict__ wof) {
  const int e = blockIdx.x * 256 + threadIdx.x;   // 0..8191
  const int l15 = e & 15, vt = (e >> 4) & 3, qq = (e >> 6) & 3, kb = e >> 8;
  #pragma unroll
  for (int j = 0; j < 8; ++j)
    wof[e * 8 + j] = f2bf(Who[(kb * 32 + qq * 8 + j) * VOC + vt * 16 + l15]);
}

// ---------------- group barrier (r0-proven) ---------------------------------
__device__ inline void group_barrier(unsigned int* cnt_i, int tid, int round) {
  __syncthreads();
  if (tid == 0) {
    atomicAdd(cnt_i, 1u);
    int guard = 0;
    while (__hip_atomic_load(cnt_i, __ATOMIC_RELAXED, __HIP_MEMORY_SCOPE_AGENT)
           < 32u * (unsigned)round) {
      __builtin_amdgcn_s_sleep(1);
      if (++guard > (1 << 16)) break;    // bailout: wrong answer beats a hang
    }
  }
  __syncthreads();
}

// ---------------- K2: persistent recurrence + paced inline logits ----------
// LDS: w_lds 65536 | h_lds 66048 (32 rows x 2064B) | p_lds 8192 | xs 128
__global__ __launch_bounds__(256, 1) void k_rnn(
    const int* __restrict__ x, const float* __restrict__ Whh,
    const float* __restrict__ proj, const unsigned short* __restrict__ wof,
    const float* __restrict__ bo, unsigned short* __restrict__ ring,
    float* __restrict__ out, float* __restrict__ final_out,
    unsigned int* __restrict__ cnt) {
  extern __shared__ char smem[];
  unsigned short* w_lds = (unsigned short*)smem;            // 65536
  char*           h_lds = smem + 65536;                     // 66048
  float*          p_lds = (float*)(smem + 131584);          // 8192
  int*            xs    = (int*)(smem + 139776);            // 128

  const int tid = threadIdx.x, bid = blockIdx.x;
  const int gi = bid & 7, gj = bid >> 3;                    // group / col-slice
  const int row0 = gi * 32;
  const int lane = tid & 63, wv = tid >> 6;
  const int mt = wv & 1, nt = wv >> 1;                      // recurrence tiles
  const int l15 = lane & 15, q = lane >> 4;

  // W_hh column slice -> LDS bf16 B-fragment order (once).
  for (int it = 0; it < 128; ++it) {
    int u = it * 256 + tid;
    int n = u & 31, j8 = (u >> 5) & 7, qq = (u >> 8) & 3, kb = u >> 10;
    w_lds[((kb * 4 + qq) * 32 + n) * 8 + j8] =
        f2bf(Whh[(kb * 32 + qq * 8 + j8) * HID + gj * 32 + n]);
  }
  // proj slice [64 vocab][32 cols] -> LDS f32 (once).
  for (int it = 0; it < 8; ++it) {
    int u = it * 256 + tid;
    p_lds[u] = proj[(u >> 5) * HID + gj * 32 + (u & 31)];
  }
  if (tid < 32) xs[tid] = x[(row0 + tid) * SEQ];
  __syncthreads();

  unsigned int* cnt_i = cnt + gi * 32;                      // 128B-strided
  const int hcol = gj * 32 + nt * 16 + l15;
  const char* abase = h_lds + (mt * 16 + l15) * 2064 + q * 16;
  const char* bbase = (const char*)w_lds + (q * 32 + nt * 16 + l15) * 16;
  const float bias = bo[wv * 16 + l15];

  // ---- paced logits state (block-uniform control) ----
  const int rbase = row0 + (gj & 1) * 16;
  const char* wofb = (const char*)wof + ((q * 4 + wv) * 16 + l15) * 16;
  int tsel = gj >> 1;                       // current task's timestep
  int kbl = 0, pend = 0;                    // chunk progress / prefetch valid
  f32x4 lc = {0.f, 0.f, 0.f, 0.f};
  u64 pf0 = 0, pf1 = 0, pf2 = 0, pf3 = 0;   // prefetched A for chunks kbl,kbl+1

  for (int t = 0; t < SEQ; ++t) {
    // 1) recurrence MFMA: 32x32 tile = h_prev(32x1024) @ Whh_slice(1024x32)
    f32x4 a0 = {0.f, 0.f, 0.f, 0.f}, a1 = {0.f, 0.f, 0.f, 0.f};
    f32x4 a2 = {0.f, 0.f, 0.f, 0.f}, a3 = {0.f, 0.f, 0.f, 0.f};
    if (t > 0) {
      #pragma unroll 2
      for (int kb = 0; kb < 32; kb += 4) {
        short8 af0 = *(const short8*)(abase + kb * 64);
        short8 bf0 = *(const short8*)(bbase + kb * 2048);
        a0 = __builtin_amdgcn_mfma_f32_16x16x32_bf16(af0, bf0, a0, 0, 0, 0);
        short8 af1 = *(const short8*)(abase + kb * 64 + 64);
        short8 bf1 = *(const short8*)(bbase + kb * 2048 + 2048);
        a1 = __builtin_amdgcn_mfma_f32_16x16x32_bf16(af1, bf1, a1, 0, 0, 0);
        short8 af2 = *(const short8*)(abase + kb * 64 + 128);
        short8 bf2 = *(const short8*)(bbase + kb * 2048 + 4096);
        a2 = __builtin_amdgcn_mfma_f32_16x16x32_bf16(af2, bf2, a2, 0, 0, 0);
        short8 af3 = *(const short8*)(abase + kb * 64 + 192);
        short8 bf3 = *(const short8*)(bbase + kb * 2048 + 6144);
        a3 = __builtin_amdgcn_mfma_f32_16x16x32_bf16(af3, bf3, a3, 0, 0, 0);
      }
    }
    // 2) epilogue: h_t = tanh(proj[x_t] + acc); publish packed col-pairs.
    unsigned short* slot = ring + (size_t)(t & (RING_SLOTS - 1)) * BH;
    float hv[4];
    #pragma unroll
    for (int r = 0; r < 4; ++r) {
      int ml = mt * 16 + q * 4 + r;                         // D row = q*4+r
      float av = (a0[r] + a1[r]) + (a2[r] + a3[r]);
      hv[r] = ftanh(p_lds[xs[ml] * 32 + nt * 16 + l15] + av);
      if (t == SEQ - 1) final_out[(row0 + ml) * HID + hcol] = hv[r];
    }
    #pragma unroll
    for (int r = 0; r < 4; ++r) {
      unsigned myb = f2bf(hv[r]);
      unsigned oth = (unsigned)__shfl_xor((int)myb, 1);
      if ((l15 & 1) == 0) {
        int b = row0 + mt * 16 + q * 4 + r;
        cstore32(slot + (size_t)b * HID + hcol, myb | (oth << 16));
      }
    }
    // 3) paced logits (PRE-barrier; data >=1 step old, flags already proven)
    if (pend) {
      union { u64 d[2]; short8 s8; } c0, c1;
      c0.d[0] = pf0; c0.d[1] = pf1;
      c1.d[0] = pf2; c1.d[1] = pf3;
      short8 w0 = *(const short8*)(wofb + (size_t)kbl * 4096);
      short8 w1 = *(const short8*)(wofb + (size_t)(kbl + 1) * 4096);
      lc = __builtin_amdgcn_mfma_f32_16x16x32_bf16(c0.s8, w0, lc, 0, 0, 0);
      lc = __builtin_amdgcn_mfma_f32_16x16x32_bf16(c1.s8, w1, lc, 0, 0, 0);
      kbl += 2; pend = 0;
    }
    if (kbl == 32) {                                        // task complete
      #pragma unroll
      for (int rr = 0; rr < 4; ++rr)
        out[((size_t)(rbase + q * 4 + rr) * SEQ + tsel) * VOC + wv * 16 + l15] =
            lc[rr] + bias;
      lc = (f32x4){0.f, 0.f, 0.f, 0.f};
      tsel += 16; kbl = 0;
    }
    if (kbl < 32 && tsel <= SEQ - 1 && t >= tsel + 1) {     // prefetch 2 chunks
      const unsigned short* hsA = ring + (size_t)(tsel & 31) * BH +
                                  (size_t)(rbase + l15) * HID + q * 8;
      pf0 = cload64(hsA + kbl * 32);       pf1 = cload64(hsA + kbl * 32 + 4);
      pf2 = cload64(hsA + kbl * 32 + 32);  pf3 = cload64(hsA + kbl * 32 + 36);
      pend = 1;
    }
    // 4) group barrier (release = __syncthreads' vmcnt(0) drain; absorbs
    //    the prefetch latency too)
    group_barrier(cnt_i, tid, t + 1);
    // 5) restage h_t (32 rows x 1024, coalesced agent loads) -> h_lds
    if (t < SEQ - 1) {
      u64 tmp[32];
      #pragma unroll
      for (int rr = 0; rr < 32; ++rr)
        tmp[rr] = cload64(slot + (size_t)(row0 + rr) * HID + tid * 4);
      #pragma unroll
      for (int rr = 0; rr < 32; ++rr)
        *(u64*)(h_lds + rr * 2064 + tid * 8) = tmp[rr];
      if (tid < 32) xs[tid] = x[(row0 + tid) * SEQ + (t + 1)];
      __syncthreads();
    }
  }

  // ---- drain remaining logits chunks (all ring data final; flags = SEQ) ----
  for (int it = 0; it < 24 && tsel <= SEQ - 1; ++it) {
    if (pend) {
      union { u64 d[2]; short8 s8; } c0, c1;
      c0.d[0] = pf0; c0.d[1] = pf1;
      c1.d[0] = pf2; c1.d[1] = pf3;
      short8 w0 = *(const short8*)(wofb + (size_t)kbl * 4096);
      short8 w1 = *(const short8*)(wofb + (size_t)(kbl + 1) * 4096);
      lc = __builtin_amdgcn_mfma_f32_16x16x32_bf16(c0.s8, w0, lc, 0, 0, 0);
      lc = __builtin_amdgcn_mfma_f32_16x16x32_bf16(c1.s8, w1, lc, 0, 0, 0);
      kbl += 2; pend = 0;
    }
    if (kbl == 32) {
      #pragma unroll
      for (int rr = 0; rr < 4; ++rr)
        out[((size_t)(rbase + q * 4 + rr) * SEQ + tsel) * VOC + wv * 16 + l15] =
            lc[rr] + bias;
      lc = (f32x4){0.f, 0.f, 0.f, 0.f};
      tsel += 16; kbl = 0;
      if (tsel > SEQ - 1) break;
    }
    if (kbl < 32) {
      const unsigned short* hsA = ring + (size_t)(tsel & 31) * BH +
                                  (size_t)(rbase + l15) * HID + q * 8;
      pf0 = cload64(hsA + kbl * 32);       pf1 = cload64(hsA + kbl * 32 + 4);
      pf2 = cload64(hsA + kbl * 32 + 32);  pf3 = cload64(hsA + kbl * 32 + 36);
      pend = 1;
    }
  }
}

// ---------------- launch ----------------------------------------------------
extern "C" void kernel_launch(void* const* d_in, const int* in_sizes, int n_in,
                              void* d_out, int out_size, void* d_ws, size_t ws_size,
                              hipStream_t stream) {
  const int*   x   = (const int*)d_in[0];
  const float* emb = (const float*)d_in[1];
  const float* Wih = (const float*)d_in[2];
  const float* Whh = (const float*)d_in[3];
  const float* bh  = (const float*)d_in[4];
  const float* Who = (const float*)d_in[5];
  const float* bo  = (const float*)d_in[6];
  float* out = (float*)d_out;

  char* ws = (char*)d_ws;
  float*          proj = (float*)ws;                         // 262144 B
  unsigned int*   cnt  = (unsigned int*)(ws + 262144);       // 1024 B
  unsigned short* wof  = (unsigned short*)(ws + 524288);     // 131072 B
  unsigned short* ring = (unsigned short*)(ws + (1 << 20));  // 16 MiB

  size_t need = (size_t)(1 << 20) + (size_t)RING_SLOTS * BATCH * HID * 2;
  if (ws_size < need) return;  // diagnostic fail (absmax) instead of a fault

  (void)hipFuncSetAttribute(reinterpret_cast<const void*>(k_rnn),
                            hipFuncAttributeMaxDynamicSharedMemorySize, 139904);

  k_prep<<<256, 256, 0, stream>>>(emb, Wih, bh, proj);
  k_prep2<<<32, 256, 0, stream>>>(Who, wof);
  hipMemsetAsync(cnt, 0, 1024, stream);
  k_rnn<<<256, 256, 139904, stream>>>(x, Whh, proj, wof, bo, ring,
                                      out, out + FINAL_OFF, cnt);
}

// Round 8
// 2174.131 us; speedup vs baseline: 2.8113x; 1.3512x over previous
//
#include <hip/hip_runtime.h>
#include <stdint.h>

// CharRNN MI355X — r0 skeleton, regrouped 16x16 blocks (R=16 rows, C=64 cols).
//   Rationale (r0-r7 evidence): sync-structure changes are all neutral/worse;
//   the remaining lever is EXCHANGE VOLUME = 256 blocks x R x 2KB per step.
//   r0: R=32 -> 16 MB/step through the MALL. Here: R=16, C=64 -> 8 MB/step,
//   16-member barriers (half the straggler pool), cleaner logits (16 blocks
//   x 16 timesteps per group).
//   Cost: W_hh slice = 1024x64 bf16 = 128KB LDS; h buffer 16x2048B = 32KB;
//   total EXACTLY 160KB -> no padding possible -> XOR-swizzled h_lds
//   (byte ^= (row&7)<<4 on both write and read; min-8 b128 bank pattern),
//   proj + x reads move to global (read-only, XCD-L2 resident).
//   Kept from r7 (numerically verified): ftanh exp identity, 4-chain accs.
//   Logits: r0's proven lumped post-barrier form, tsel = t-15+gj (gj 0..15).
// d_ws: proj f32 @0 (256KB) | cnt @262144 (1KB) | wof @524288 (128KB)
//       | ring bf16 @1MB (16MB)

#define BATCH 256
#define SEQ   512
#define HID   1024
#define VOC   64
#define EMB   256
#define FINAL_OFF (BATCH * SEQ * VOC)   // 8388608
#define RING_SLOTS 32
#define BH (BATCH * HID)

typedef __attribute__((ext_vector_type(8))) short short8;
typedef __attribute__((ext_vector_type(4))) float f32x4;
typedef unsigned long long u64;

__device__ inline unsigned short f2bf(float f) {
  union { float f; unsigned u; } v; v.f = f;
  unsigned u = v.u;
  return (unsigned short)((u + 0x7FFFu + ((u >> 16) & 1u)) >> 16);  // RNE
}

// branch-free tanh: 1 - 2/(e^{2x}+1). Verified r7 (absmax unchanged).
__device__ __forceinline__ float ftanh(float v) {
  float e = __expf(2.0f * v);
  return fmaf(-2.0f, __builtin_amdgcn_rcpf(e + 1.0f), 1.0f);
}

// ---- agent-scope (MALL-point) ops — the PROVEN coherence class -------------
__device__ inline u64 cload64(const unsigned short* p) {
  return __hip_atomic_load((const u64*)p, __ATOMIC_RELAXED,
                           __HIP_MEMORY_SCOPE_AGENT);
}
__device__ inline void cstore32(unsigned short* p, unsigned v) {
  __hip_atomic_store((unsigned*)p, v, __ATOMIC_RELAXED,
                     __HIP_MEMORY_SCOPE_AGENT);
}

// ---------------- K1: projection table -------------------------------------
__global__ __launch_bounds__(256) void k_prep(const float* __restrict__ emb,
                                              const float* __restrict__ Wih,
                                              const float* __restrict__ bh,
                                              float* __restrict__ proj) {
  __shared__ float es[EMB];
  const int v = blockIdx.x >> 2;        // 0..63
  const int p = blockIdx.x & 3;         // h-quarter
  const int tid = threadIdx.x;
  es[tid] = emb[v * EMB + tid];
  __syncthreads();
  const int h = p * 256 + tid;
  float acc = bh[h];
  for (int e = 0; e < EMB; ++e) acc += es[e] * Wih[e * HID + h];
  proj[v * HID + h] = acc;
}

// ---------------- K1b: W_ho bf16 fragment table (r6/r7-proven) --------------
// entry e = ((kb*4+q)*4+vt)*16 + l15 ; elems j: Who[(kb*32+q*8+j)*VOC+vt*16+l15]
__global__ __launch_bounds__(256) void k_prep2(const float* __restrict__ Who,
                                               unsigned short* __restrict__ wof) {
  const int e = blockIdx.x * 256 + threadIdx.x;   // 0..8191
  const int l15 = e & 15, vt = (e >> 4) & 3, qq = (e >> 6) & 3, kb = e >> 8;
  #pragma unroll
  for (int j = 0; j < 8; ++j)
    wof[e * 8 + j] = f2bf(Who[(kb * 32 + qq * 8 + j) * VOC + vt * 16 + l15]);
}

// ---------------- group barrier (r0-proven; 16 members now) -----------------
__device__ inline void group_barrier(unsigned int* cnt_i, int tid, int round) {
  __syncthreads();
  if (tid == 0) {
    atomicAdd(cnt_i, 1u);
    int guard = 0;
    while (__hip_atomic_load(cnt_i, __ATOMIC_RELAXED, __HIP_MEMORY_SCOPE_AGENT)
           < 16u * (unsigned)round) {
      __builtin_amdgcn_s_sleep(1);
      if (++guard > (1 << 16)) break;    // bailout: wrong answer beats a hang
    }
  }
  __syncthreads();
}

// ---------------- K2: persistent recurrence + inline logits ----------------
// LDS: w_lds 131072 (1024x64 bf16 B-frags) | h_lds 32768 (16 x 2048B, XOR swz)
__global__ __launch_bounds__(256, 1) void k_rnn(
    const int* __restrict__ x, const float* __restrict__ Whh,
    const float* __restrict__ proj, const unsigned short* __restrict__ wof,
    const float* __restrict__ bo, unsigned short* __restrict__ ring,
    float* __restrict__ out, float* __restrict__ final_out,
    unsigned int* __restrict__ cnt) {
  extern __shared__ char smem[];
  unsigned short* w_lds = (unsigned short*)smem;            // 131072
  char*           h_lds = smem + 131072;                    // 32768

  const int tid = threadIdx.x, bid = blockIdx.x;
  const int gi = bid & 15, gj = bid >> 4;   // group (16 rows) / col-slice (64)
  const int row0 = gi * 16;
  const int lane = tid & 63, wv = tid >> 6;                 // wv = nt slice
  const int l15 = lane & 15, q = lane >> 4;

  // W_hh column slice (1024 x 64) -> LDS bf16 B-fragment order (once).
  // byte = kb*4096 + qq*1024 + n*16 + j8*2
  for (int it = 0; it < 256; ++it) {
    int u = it * 256 + tid;               // 0..65535
    int k = u >> 6, n = u & 63;           // coalesced over n
    int kb = k >> 5, qq = (k >> 3) & 3, j8 = k & 7;
    w_lds[(size_t)kb * 2048 + qq * 512 + n * 8 + j8] =
        f2bf(Whh[k * HID + gj * 64 + n]);
  }
  __syncthreads();

  unsigned int* cnt_i = cnt + gi * 32;                      // 128B-strided
  const int hcol = gj * 64 + wv * 16 + l15;
  const int swzkey = (l15 & 7) << 4;                        // h_lds read key
  const char* abase = h_lds + l15 * 2048;
  const char* bbase = (const char*)w_lds + q * 1024 + (wv * 16 + l15) * 16;
  const float bias = bo[wv * 16 + l15];
  const char* wofb = (const char*)wof + ((q * 4 + wv) * 16 + l15) * 16;

  for (int t = 0; t < SEQ; ++t) {
    int xv = (lane < 16) ? x[(row0 + lane) * SEQ + t] : 0;
    // 1) recurrence MFMA: 16x16 tile (rows row0..+16 x cols wv-slice), K=1024
    f32x4 a0 = {0.f, 0.f, 0.f, 0.f}, a1 = {0.f, 0.f, 0.f, 0.f};
    f32x4 a2 = {0.f, 0.f, 0.f, 0.f}, a3 = {0.f, 0.f, 0.f, 0.f};
    if (t > 0) {
      #pragma unroll 2
      for (int kb = 0; kb < 32; kb += 4) {
        short8 af0 = *(const short8*)(abase + (((kb + 0) * 64 + q * 16) ^ swzkey));
        short8 bf0 = *(const short8*)(bbase + (kb + 0) * 4096);
        a0 = __builtin_amdgcn_mfma_f32_16x16x32_bf16(af0, bf0, a0, 0, 0, 0);
        short8 af1 = *(const short8*)(abase + (((kb + 1) * 64 + q * 16) ^ swzkey));
        short8 bf1 = *(const short8*)(bbase + (kb + 1) * 4096);
        a1 = __builtin_amdgcn_mfma_f32_16x16x32_bf16(af1, bf1, a1, 0, 0, 0);
        short8 af2 = *(const short8*)(abase + (((kb + 2) * 64 + q * 16) ^ swzkey));
        short8 bf2 = *(const short8*)(bbase + (kb + 2) * 4096);
        a2 = __builtin_amdgcn_mfma_f32_16x16x32_bf16(af2, bf2, a2, 0, 0, 0);
        short8 af3 = *(const short8*)(abase + (((kb + 3) * 64 + q * 16) ^ swzkey));
        short8 bf3 = *(const short8*)(bbase + (kb + 3) * 4096);
        a3 = __builtin_amdgcn_mfma_f32_16x16x32_bf16(af3, bf3, a3, 0, 0, 0);
      }
    }
    // 2) epilogue: h_t = tanh(proj[x_t] + acc); publish packed col-pairs.
    unsigned short* slot = ring + (size_t)(t & (RING_SLOTS - 1)) * BH;
    float hv[4];
    #pragma unroll
    for (int r = 0; r < 4; ++r) {
      int row = q * 4 + r;                                  // D row
      int xi = __shfl(xv, row);
      float av = (a0[r] + a1[r]) + (a2[r] + a3[r]);
      hv[r] = ftanh(proj[(size_t)xi * HID + hcol] + av);
      if (t == SEQ - 1) final_out[(size_t)(row0 + row) * HID + hcol] = hv[r];
    }
    #pragma unroll
    for (int r = 0; r < 4; ++r) {
      unsigned myb = f2bf(hv[r]);
      unsigned oth = (unsigned)__shfl_xor((int)myb, 1);
      if ((l15 & 1) == 0) {
        int b = row0 + q * 4 + r;
        cstore32(slot + (size_t)b * HID + hcol, myb | (oth << 16));
      }
    }
    // 3) group barrier (release = __syncthreads' vmcnt(0) drain)
    group_barrier(cnt_i, tid, t + 1);
    // 4) lumped logits every 16 steps: 16 rows x 1 timestep x 64 voc.
    //    tsel = t-15+gj <= t, guaranteed complete by the barrier just passed.
    if ((t & 15) == 15) {
      int tsel = (t - 15) + gj;
      const unsigned short* hs =
          ring + (size_t)(tsel & (RING_SLOTS - 1)) * BH +
          (size_t)(row0 + l15) * HID + q * 8;               // A row base
      f32x4 lc = {0.f, 0.f, 0.f, 0.f};
      for (int g = 0; g < 4; ++g) {
        u64 hb[16];
        #pragma unroll
        for (int j = 0; j < 8; ++j) {
          const unsigned short* pk = hs + (g * 8 + j) * 32;
          hb[2 * j]     = cload64(pk);
          hb[2 * j + 1] = cload64(pk + 4);
        }
        #pragma unroll
        for (int j = 0; j < 8; ++j) {
          union { u64 d[2]; short8 s8; } c;
          c.d[0] = hb[2 * j]; c.d[1] = hb[2 * j + 1];
          short8 w8 = *(const short8*)(wofb + (size_t)(g * 8 + j) * 4096);
          lc = __builtin_amdgcn_mfma_f32_16x16x32_bf16(c.s8, w8, lc, 0, 0, 0);
        }
      }
      #pragma unroll
      for (int rr = 0; rr < 4; ++rr) {
        int b = row0 + q * 4 + rr;
        out[((size_t)b * SEQ + tsel) * VOC + wv * 16 + l15] = lc[rr] + bias;
      }
      // reuse safe: read slot tsel >= t-15 > t-32
    }
    // 5) restage h_t (16 rows x 1024, coalesced agent loads) -> h_lds (XOR swz)
    if (t < SEQ - 1) {
      u64 tmp[16];
      #pragma unroll
      for (int rr = 0; rr < 16; ++rr)
        tmp[rr] = cload64(slot + (size_t)(row0 + rr) * HID + tid * 4);
      #pragma unroll
      for (int rr = 0; rr < 16; ++rr)
        *(u64*)(h_lds + rr * 2048 + ((tid * 8) ^ ((rr & 7) << 4))) = tmp[rr];
      __syncthreads();
    }
  }
}

// ---------------- launch ----------------------------------------------------
extern "C" void kernel_launch(void* const* d_in, const int* in_sizes, int n_in,
                              void* d_out, int out_size, void* d_ws, size_t ws_size,
                              hipStream_t stream) {
  const int*   x   = (const int*)d_in[0];
  const float* emb = (const float*)d_in[1];
  const float* Wih = (const float*)d_in[2];
  const float* Whh = (const float*)d_in[3];
  const float* bh  = (const float*)d_in[4];
  const float* Who = (const float*)d_in[5];
  const float* bo  = (const float*)d_in[6];
  float* out = (float*)d_out;

  char* ws = (char*)d_ws;
  float*          proj = (float*)ws;                         // 262144 B
  unsigned int*   cnt  = (unsigned int*)(ws + 262144);       // 4096 B
  unsigned short* wof  = (unsigned short*)(ws + 524288);     // 131072 B
  unsigned short* ring = (unsigned short*)(ws + (1 << 20));  // 16 MiB

  size_t need = (size_t)(1 << 20) + (size_t)RING_SLOTS * BATCH * HID * 2;
  if (ws_size < need) return;  // diagnostic fail (absmax) instead of a fault

  (void)hipFuncSetAttribute(reinterpret_cast<const void*>(k_rnn),
                            hipFuncAttributeMaxDynamicSharedMemorySize, 163840);

  k_prep<<<256, 256, 0, stream>>>(emb, Wih, bh, proj);
  k_prep2<<<32, 256, 0, stream>>>(Who, wof);
  hipMemsetAsync(cnt, 0, 4096, stream);
  k_rnn<<<256, 256, 163840, stream>>>(x, Whh, proj, wof, bo, ring,
                                      out, out + FINAL_OFF, cnt);
}